// Round 9
// baseline (254.735 us; speedup 1.0000x reference)
//
#include <hip/hip_runtime.h>

typedef _Float16 half8  __attribute__((ext_vector_type(8)));
typedef _Float16 half4v __attribute__((ext_vector_type(4)));
typedef float    float4v __attribute__((ext_vector_type(4)));

#define N_ 4096
#define B_ 8
#define D_ 64
#define F_ 128

// ---------------- K1: pack adjacency to bitmask (int4 = 16B/lane) ----------------
__global__ __launch_bounds__(256) void pack_adj_kernel(const int4* __restrict__ adj4,
                                                       unsigned long long* __restrict__ bits) {
  __shared__ unsigned char nib[256];
  const int t = threadIdx.x;
  int4 v = adj4[(size_t)blockIdx.x * 256 + t];
  unsigned n = (v.x > 0 ? 1u : 0u) | (v.y > 0 ? 2u : 0u) |
               (v.z > 0 ? 4u : 0u) | (v.w > 0 ? 8u : 0u);
  nib[t] = (unsigned char)n;
  __syncthreads();
  if (t < 16) {
    const unsigned char* p = &nib[t * 16];
    unsigned long long wv = 0;
#pragma unroll
    for (int i = 0; i < 16; ++i) wv |= (unsigned long long)p[i] << (4 * i);
    bits[(size_t)blockIdx.x * 16 + t] = wv;
  }
}

// ---------------- K2: Wh = h @ W via MFMA (h->fp16), dual store Wh/WhT ----------------
__global__ __launch_bounds__(256) void wh_kernel(const float* __restrict__ h,
                                                 const float* __restrict__ W,
                                                 _Float16* __restrict__ Wh16,
                                                 _Float16* __restrict__ WhT16) {
  __shared__ __align__(16) _Float16 hs[64 * 128];
  __shared__ __align__(16) _Float16 wt[64 * 128];
  __shared__ __align__(16) _Float16 otile[64][72];
  const int t = threadIdx.x;
  const int rowbase = blockIdx.x * 64;
#pragma unroll
  for (int i = 0; i < 4; ++i) {
    int e = i * 256 + t;
    int r = e >> 4, kb = e & 15;
    const float4v* src = (const float4v*)(h + (size_t)(rowbase + r) * F_ + kb * 8);
    float4v a = src[0], b = src[1];
    uint4 pk;
    pk.x = __builtin_bit_cast(unsigned, __builtin_amdgcn_cvt_pkrtz(a[0], a[1]));
    pk.y = __builtin_bit_cast(unsigned, __builtin_amdgcn_cvt_pkrtz(a[2], a[3]));
    pk.z = __builtin_bit_cast(unsigned, __builtin_amdgcn_cvt_pkrtz(b[0], b[1]));
    pk.w = __builtin_bit_cast(unsigned, __builtin_amdgcn_cvt_pkrtz(b[2], b[3]));
    *(uint4*)&hs[(r * 16 + (kb ^ (r & 7))) * 8] = pk;
  }
#pragma unroll
  for (int k = 0; k < 8; ++k) {
    int i4 = t + k * 256;
    float4v v = ((const float4v*)W)[i4];
    int f = i4 >> 4, c4 = (i4 & 15) * 4;
    int oct = f >> 3, ki = f & 7;
#pragma unroll
    for (int j = 0; j < 4; ++j) {
      int c = c4 + j;
      wt[(c * 16 + (oct ^ (c & 7))) * 8 + ki] = (_Float16)v[j];
    }
  }
  __syncthreads();
  const int w = t >> 6, lane = t & 63;
  const int g = lane >> 4, c = lane & 15;
  const int r0 = w * 16;
  const int arow = r0 + c, aswz = arow & 7;
  half8 af[4];
#pragma unroll
  for (int kk = 0; kk < 4; ++kk)
    af[kk] = *(half8*)&hs[(arow * 16 + ((kk * 4 + g) ^ aswz)) * 8];
  float4v acc[4];
#pragma unroll
  for (int cb = 0; cb < 4; ++cb) {
    float4v z = (float4v){0.f, 0.f, 0.f, 0.f};
    const int bcol = cb * 16 + c, bswz = c & 7;
#pragma unroll
    for (int kk = 0; kk < 4; ++kk) {
      half8 bf = *(half8*)&wt[(bcol * 16 + ((kk * 4 + g) ^ bswz)) * 8];
      z = __builtin_amdgcn_mfma_f32_16x16x32_f16(af[kk], bf, z, 0, 0, 0);
    }
    acc[cb] = z;
  }
  __syncthreads();
#pragma unroll
  for (int cb = 0; cb < 4; ++cb)
#pragma unroll
    for (int j = 0; j < 4; ++j)
      otile[r0 + g * 4 + j][cb * 16 + c] = (_Float16)acc[cb][j];
  __syncthreads();
  const int rr = t >> 2, c0 = (t & 3) * 16;
  half8 w0 = *(half8*)&otile[rr][c0];
  half8 w1 = *(half8*)&otile[rr][c0 + 8];
  _Float16* dW = Wh16 + (size_t)(rowbase + rr) * D_ + c0;
  *(half8*)dW       = w0;
  *(half8*)(dW + 8) = w1;
  const int dl = t >> 2, k0t = (t & 3) * 16;
  half8 o0, o1;
#pragma unroll
  for (int i = 0; i < 8; ++i) o0[i] = otile[k0t + i][dl];
#pragma unroll
  for (int i = 0; i < 8; ++i) o1[i] = otile[k0t + 8 + i][dl];
  const int b = rowbase >> 12, n0 = rowbase & 4095;
  _Float16* dst = WhT16 + ((size_t)(b * D_ + dl)) * N_ + n0 + k0t;
  *(half8*)dst       = o0;
  *(half8*)(dst + 8) = o1;
}

// ---------------- K3: flash attention + ELU ----------------
// 1024 thr = 16 waves: 4 q-chunks(16 rows) x 4 KV-quarters (split-K 4-way).
// KVBLK=32. Per-group K(4K)+V(4K) double-buffered = 64K + P 16K = 80K LDS
// -> 2 blocks/CU = 32 waves/CU (8/SIMD, vs 4 in round 8). Grid 512 (same
// L2 traffic as round 8). V swizzle rank-2 XOR ((c^(c>>2))&3), <=2-way free.
__global__ __launch_bounds__(1024, 8) void attn_kernel(
    const unsigned long long* __restrict__ bits,
    const _Float16* __restrict__ Wh,
    const _Float16* __restrict__ WhT,
    float* __restrict__ out) {
  __shared__ __align__(16) char lds[81920];
  const int tid  = threadIdx.x;
  const int w    = tid >> 6;
  const int lane = tid & 63;
  const int g    = lane >> 4;
  const int c    = lane & 15;
  const int qi   = w & 3;
  const int s    = w >> 2;                      // KV quarter 0..3
  const int bid  = blockIdx.x;
  const int b    = bid >> 6;
  const int q0b  = (bid & 63) * 64;
  const int q0w  = q0b + qi * 16;

  const _Float16* Whb  = Wh  + (size_t)b * N_ * D_;
  const _Float16* WhTb = WhT + (size_t)b * D_ * N_;
  char* Kgrp = lds + s * 16384;                 // [K0 4K][V0 4K][K1 4K][V1 4K]
  char* Pb   = lds + 65536 + w * 1024;

  // group-local staging id (4 waves = 256 thr per group)
  const int li  = qi * 64 + lane;
  const int rK  = li >> 3, oK = (li & 7) ^ (rK & 7);            // K: 32 rows x 8 octets
  const int rV  = li >> 2, oV = (li & 3) ^ ((rV ^ (rV >> 2)) & 3); // V: 64 rows x 4 octets
  const int vswz = (c ^ (c >> 2)) & 3;

  half8 qf[2];
#pragma unroll
  for (int ds = 0; ds < 2; ++ds) {
    half8 v = *(const half8*)(Whb + (size_t)(q0w + c) * D_ + ds * 32 + g * 8);
    qf[ds] = v * (_Float16)0.18033688f;         // (1/8)*log2(e)
  }

  float4v o_acc[4];
#pragma unroll
  for (int d = 0; d < 4; ++d) o_acc[d] = (float4v){0.f, 0.f, 0.f, 0.f};
  float mrow = -1e30f, lrow = 0.f;

  const unsigned* bqp = (const unsigned*)bits + (size_t)(q0w + c) * 128 + s * 32;

  // affine staging pointers; quarter base k0s = s*1024
  const _Float16* pk = Whb + (size_t)(s * 1024 + rK) * D_ + oK * 8;
  const _Float16* pv = WhTb + (size_t)rV * N_ + s * 1024 + oV * 8;

  // stage tile 0 into buffer 0
  *(half8*)(Kgrp + li * 16)        = *(const half8*)pk;
  *(half8*)(Kgrp + 4096 + li * 16) = *(const half8*)pv;
  unsigned bw = bqp[0];
  __syncthreads();

#define COMPUTE_TILE(CUR)                                                        \
  {                                                                              \
    const _Float16* Kc = (const _Float16*)(Kgrp + (CUR));                        \
    const _Float16* Vc = (const _Float16*)(Kgrp + 4096 + (CUR));                 \
    float4v sac[2];                                                              \
    __builtin_amdgcn_s_setprio(1);                                               \
    _Pragma("unroll")                                                            \
    for (int st = 0; st < 2; ++st) {                                             \
      const _Float16* kr = Kc + (st * 16 + c) * 64;                              \
      half8 kf0 = *(const half8*)(kr + ((g       ^ (c & 7)) * 8));               \
      half8 kf1 = *(const half8*)(kr + (((g + 4) ^ (c & 7)) * 8));               \
      float4v z = (float4v){0.f, 0.f, 0.f, 0.f};                                 \
      z = __builtin_amdgcn_mfma_f32_16x16x32_f16(kf0, qf[0], z, 0, 0, 0);        \
      z = __builtin_amdgcn_mfma_f32_16x16x32_f16(kf1, qf[1], z, 0, 0, 0);        \
      sac[st] = z;                                                               \
    }                                                                            \
    __builtin_amdgcn_s_setprio(0);                                               \
    _Pragma("unroll")                                                            \
    for (int st = 0; st < 2; ++st) {                                             \
      unsigned wb = bw >> (st * 16 + g * 4);                                     \
      _Pragma("unroll")                                                          \
      for (int j = 0; j < 4; ++j)                                                \
        sac[st][j] = (wb & (1u << j)) ? sac[st][j] : -1e9f;                      \
    }                                                                            \
    float tmax = fmaxf(                                                          \
        fmaxf(fmaxf(sac[0][0], sac[0][1]), fmaxf(sac[0][2], sac[0][3])),         \
        fmaxf(fmaxf(sac[1][0], sac[1][1]), fmaxf(sac[1][2], sac[1][3])));        \
    tmax = fmaxf(tmax, __shfl_xor(tmax, 16));                                    \
    tmax = fmaxf(tmax, __shfl_xor(tmax, 32));                                    \
    if (__any(tmax > mrow)) {                                                    \
      float mnew  = fmaxf(mrow, tmax);                                           \
      float alpha = exp2f(mrow - mnew);                                          \
      mrow = mnew;                                                               \
      lrow *= alpha;                                                             \
      _Pragma("unroll")                                                          \
      for (int j = 0; j < 4; ++j) {                                              \
        float aj = __shfl(alpha, (lane & 48) | (g * 4 + j));                     \
        _Pragma("unroll")                                                        \
        for (int d = 0; d < 4; ++d) o_acc[d][j] *= aj;                           \
      }                                                                          \
    }                                                                            \
    _Pragma("unroll")                                                            \
    for (int st = 0; st < 2; ++st) {                                             \
      float p0 = exp2f(sac[st][0] - mrow);                                       \
      float p1 = exp2f(sac[st][1] - mrow);                                       \
      float p2 = exp2f(sac[st][2] - mrow);                                       \
      float p3 = exp2f(sac[st][3] - mrow);                                       \
      lrow += (p0 + p1) + (p2 + p3);                                             \
      uint2 pr;                                                                  \
      pr.x = __builtin_bit_cast(unsigned, __builtin_amdgcn_cvt_pkrtz(p0, p1));   \
      pr.y = __builtin_bit_cast(unsigned, __builtin_amdgcn_cvt_pkrtz(p2, p3));   \
      const int cell = st * 2 + (g >> 1);                                        \
      *(uint2*)(Pb + (cell * 16 + c) * 16 + (g & 1) * 8) = pr;                   \
    }                                                                            \
    half8 afp = *(const half8*)(Pb + (g * 16 + c) * 16);                         \
    __builtin_amdgcn_s_setprio(1);                                               \
    _Pragma("unroll")                                                            \
    for (int d = 0; d < 4; ++d) {                                                \
      half8 vf = *(const half8*)(Vc + ((d * 16 + c) * 4 + (g ^ vswz)) * 8);      \
      o_acc[d] = __builtin_amdgcn_mfma_f32_16x16x32_f16(afp, vf, o_acc[d],       \
                                                        0, 0, 0);                \
    }                                                                            \
    __builtin_amdgcn_s_setprio(0);                                               \
  }

  int cur = 0;
#pragma unroll 2
  for (int t = 0; t < 31; ++t) {
    pk += 32 * D_;
    pv += 32;
    half8 ka = *(const half8*)pk;
    half8 va = *(const half8*)pv;
    unsigned bwn = bqp[t + 1];

    COMPUTE_TILE(cur)

    const int nxt = cur ^ 8192;
    *(half8*)(Kgrp + nxt + li * 16)        = ka;
    *(half8*)(Kgrp + nxt + 4096 + li * 16) = va;
    __syncthreads();                            // one barrier per tile
    cur = nxt;
    bw = bwn;
  }
  COMPUTE_TILE(cur)
#undef COMPUTE_TILE

  // ---- epilogue: reduce l, merge 4 KV-quarter partials, ELU, store ----
  lrow += __shfl_xor(lrow, 16);
  lrow += __shfl_xor(lrow, 32);
  __syncthreads();                              // all staging/P reads done
  float* Ob = (float*)lds;                      // [256][66] fp32 (wave-slot rows)
#pragma unroll
  for (int d = 0; d < 4; ++d)
#pragma unroll
    for (int j = 0; j < 4; ++j)
      Ob[(w * 16 + g * 4 + j) * 66 + d * 16 + c] = o_acc[d][j];
  float2* mlb = (float2*)(lds + 67584);         // 256 x {m,l}
  if (g == 0) mlb[w * 16 + c] = make_float2(mrow, lrow);
  __syncthreads();

#pragma unroll
  for (int it = 0; it < 4; ++it) {
    int idx = tid + it * 1024;                  // 64 rows x 64 cols
    int r = idx >> 6, col = idx & 63;
    int qq = r >> 4, rl = r & 15;
    float2 ml[4];
    float mm = -1e30f;
#pragma unroll
    for (int p = 0; p < 4; ++p) {
      ml[p] = mlb[(p * 4 + qq) * 16 + rl];
      mm = fmaxf(mm, ml[p].x);
    }
    float l = 0.f, o = 0.f;
#pragma unroll
    for (int p = 0; p < 4; ++p) {
      float a = exp2f(ml[p].x - mm);
      l += a * ml[p].y;
      o += a * Ob[((p * 4 + qq) * 16 + rl) * 66 + col];
    }
    float x = o / l;
    x = x > 0.f ? x : (__expf(x) - 1.f);
    out[((size_t)b * N_ + q0b + r) * D_ + col] = x;
  }
}

extern "C" void kernel_launch(void* const* d_in, const int* in_sizes, int n_in,
                              void* d_out, int out_size, void* d_ws, size_t ws_size,
                              hipStream_t stream) {
  const float* h = (const float*)d_in[0];
  const float* W = (const float*)d_in[1];
  const int* adj = (const int*)d_in[2];
  float* out = (float*)d_out;

  char* ws = (char*)d_ws;
  unsigned long long* bits = (unsigned long long*)ws;      // 2 MiB
  _Float16* Wh16  = (_Float16*)(ws + (2u << 20));          // 4 MiB
  _Float16* WhT16 = (_Float16*)(ws + (6u << 20));          // 4 MiB

  hipLaunchKernelGGL(pack_adj_kernel, dim3((N_ * N_) / 1024), dim3(256), 0, stream,
                     (const int4*)adj, bits);
  hipLaunchKernelGGL(wh_kernel,   dim3((B_ * N_) / 64), dim3(256), 0, stream, h, W, Wh16, WhT16);
  hipLaunchKernelGGL(attn_kernel, dim3(B_ * (N_ / 64)), dim3(1024), 0, stream, bits, Wh16, WhT16, out);
}